// Round 7
// baseline (506.537 us; speedup 1.0000x reference)
//
#include <hip/hip_runtime.h>
#include <hip/hip_bf16.h>
#include <cstdint>
#include <cstddef>

typedef unsigned short u16;
typedef unsigned int u32;
typedef short bf16x8 __attribute__((ext_vector_type(8)));
typedef float f32x4 __attribute__((ext_vector_type(4)));
typedef float f32x2 __attribute__((ext_vector_type(2)));

static constexpr int Bb = 4, Tt = 2048, Dd = 1024, NFf = 512, NBb = 4;
static constexpr int Mm = Bb * Tt;      // 8192 tokens
static constexpr int NZz = 4736;        // packed projection width (4613 padded to 37*128)
static constexpr int Lc = 32;           // conv kernel support (|A|<=0.59 -> 0.59^32 ~ 5e-8)

#define DEV __device__ __forceinline__

typedef const __attribute__((address_space(1))) u32* gas_p;
typedef __attribute__((address_space(3))) u32* las_p;

DEV u16 f2bf(float f) {
    uint32_t u = __float_as_uint(f);
    u = (u + 0x7FFF + ((u >> 16) & 1)) >> 16;   // RNE
    return (u16)u;
}
DEV float bf2f(u16 h) { return __uint_as_float(((uint32_t)h) << 16); }
DEV float sigm(float x) { return 1.0f / (1.0f + __expf(-x)); }
DEV float gelu_ex(float t) { return 0.5f * t * (1.0f + erff(t * 0.70710678118f)); }

// ---------------------------------------------------------------- sizes
static constexpr int NW0 = NZz * Dd;        // wcat elements
static constexpr int NW1 = Dd * 2 * NFf;    // wfs
static constexpr int NW2 = 4 * Dd * Dd;     // w1
static constexpr int NW3 = 4 * Dd * Dd;     // w2
static constexpr int NWB_CAT = NW0 / 1024;  // wcat convert blocks (float4 per thread)
static constexpr int NCVT = (NW1 + NW2 + NW3) / 1024;   // 9216 deferred convert blocks

// ---------------------------------------------------------------- prep_all: freq consts + wcat cvt + LN1
__global__ __launch_bounds__(256) void prep_all(
    const float* __restrict__ Wconcept, const float* __restrict__ Wcg,
    const float* __restrict__ Wfg, const float* __restrict__ Wgate,
    const float* __restrict__ Wsp, const float* __restrict__ Wtg,
    const float* __restrict__ Wband,
    const float* __restrict__ bconcept, const float* __restrict__ bcg,
    const float* __restrict__ bfg, const float* __restrict__ bgate,
    const float* __restrict__ btg, const float* __restrict__ bband,
    const float* __restrict__ fi, const float* __restrict__ logd,
    const float* __restrict__ freqs, const float* __restrict__ dtv,
    const float* __restrict__ x, const float* __restrict__ norm_g,
    const float* __restrict__ norm_b,
    u16* __restrict__ wcat, float* __restrict__ bias_cat,
    float* __restrict__ rr, float* __restrict__ ri,
    float* __restrict__ Ar, float* __restrict__ Ai,
    u16* __restrict__ xn)
{
    const int bx = blockIdx.x;
    if (bx == 0) {
        __shared__ float red[256];
        int t = threadIdx.x;
        float v0 = fi[t], v1 = fi[t + 256];
        red[t] = fmaxf(v0, v1); __syncthreads();
        for (int s = 128; s; s >>= 1) { if (t < s) red[t] = fmaxf(red[t], red[t + s]); __syncthreads(); }
        float mx = red[0]; __syncthreads();
        float e0 = expf(v0 - mx), e1 = expf(v1 - mx);
        red[t] = e0 + e1; __syncthreads();
        for (int s = 128; s; s >>= 1) { if (t < s) red[t] += red[t + s]; __syncthreads(); }
        float inv = 1.0f / red[0];
#pragma unroll
        for (int k = 0; k < 2; k++) {
            int f = t + k * 256;
            float e = k ? e1 : e0;
            float decay = sigm(logd[f]) * (e * inv * (float)NFf);
            float omega = freqs[f] * 0.1f * (sigm(dtv[f]) * 2.0f);
            float cc = cosf(omega), ss = sinf(omega);
            rr[f] = cc; ri[f] = ss; Ar[f] = decay * cc; Ai[f] = decay * ss;
        }
        return;
    }
    if (bx <= NWB_CAT) {
        const int i = ((bx - 1) * 256 + threadIdx.x) * 4;   // 4 consecutive elements of wcat
        int r = i >> 10, c = i & 1023;
        float4 v = {0.f, 0.f, 0.f, 0.f};
        if      (r < 1024) v = *(const float4*)(Wconcept + r * 1024 + c);
        else if (r < 2048) v = *(const float4*)(Wcg + (r - 1024) * 1024 + c);
        else if (r < 2560) v = *(const float4*)(Wfg + (r - 2048) * 1024 + c);
        else if (r < 3584) v = *(const float4*)(Wgate + (r - 2560) * 1024 + c);
        else if (r < 4608) v = *(const float4*)(Wsp + (r - 3584) * 1024 + c);
        else if (r == 4608) v = *(const float4*)(Wtg + c);
        else if (r < 4613) v = *(const float4*)(Wband + (r - 4609) * 1024 + c);
        *(ushort4*)(wcat + i) = ushort4{f2bf(v.x), f2bf(v.y), f2bf(v.z), f2bf(v.w)};
        if (c == 0) {
            float bv;
            if      (r < 1024) bv = bconcept[r];
            else if (r < 2048) bv = bcg[r - 1024];
            else if (r < 2560) bv = bfg[r - 2048];
            else if (r < 3584) bv = bgate[r - 2560];
            else if (r < 4608) bv = 0.0f;
            else if (r == 4608) bv = btg[0];
            else if (r < 4613) bv = bband[r - 4609];
            else bv = 0.0f;
            bias_cat[r] = bv;
        }
        return;
    }
    // LN1 role: one block per token row
    const int m = bx - NWB_CAT - 1, tid = threadIdx.x;
    float4 v = ((const float4*)(x + (size_t)m * Dd))[tid];
    float s1 = v.x + v.y + v.z + v.w;
    float s2 = v.x * v.x + v.y * v.y + v.z * v.z + v.w * v.w;
    __shared__ float lds[16];
    for (int o = 32; o; o >>= 1) { s1 += __shfl_down(s1, o); s2 += __shfl_down(s2, o); }
    int lane = tid & 63, w = tid >> 6;
    if (!lane) { lds[w] = s1; lds[8 + w] = s2; }
    __syncthreads();
    s1 = lds[0] + lds[1] + lds[2] + lds[3];
    s2 = lds[8] + lds[9] + lds[10] + lds[11];
    float mean = s1 * (1.0f / Dd);
    float var  = s2 * (1.0f / Dd) - mean * mean;
    float rstd = rsqrtf(var + 1e-5f);
    float4 gv = ((const float4*)norm_g)[tid];
    float4 bv = ((const float4*)norm_b)[tid];
    ushort4 o;
    o.x = f2bf((v.x - mean) * rstd * gv.x + bv.x);
    o.y = f2bf((v.y - mean) * rstd * gv.y + bv.y);
    o.z = f2bf((v.z - mean) * rstd * gv.z + bv.z);
    o.w = f2bf((v.w - mean) * rstd * gv.w + bv.w);
    ((ushort4*)(xn + (size_t)m * Dd))[tid] = o;
}

// ---------------------------------------------------------------- GEMM body (bf16 MFMA, BK=64, xor-swizzled LDS)
// MODE 0: bf16 = acc + bias[n]   MODE 2: bf16 = gelu(acc+bias)   MODE 4: bf16 = acc
// MODE 3: f32 = acc + bias[n] + bf2f(addb[m,n]) — LDS-transpose epilogue (needs u16[16896] contiguous)
// MODE 5: fuse2 epilogue via LDS transpose (needs contiguous 32 KB [128][128])
template<int MODE>
DEV void gemm_body(int m0, int n0,
                   u16* __restrict__ smA, u16* __restrict__ smB,
                   const u16* __restrict__ A, const u16* __restrict__ Bw,
                   const float* __restrict__ bias, const u16* __restrict__ addb,
                   void* __restrict__ Cout, int M, int N, int K,
                   const float* __restrict__ xres = nullptr,
                   const u16* __restrict__ Zf = nullptr,
                   const float* __restrict__ oscp = nullptr,
                   f32x2* __restrict__ psums = nullptr)
{
    const int tid = threadIdx.x;
    const int w = tid >> 6, lane = tid & 63;
    const int wr = w >> 1, wc = w & 1;
    const int quad = lane >> 4, l16 = lane & 15;

    // staging: thread t -> tile row (t>>3) + 32*j; global chunk (t&7)^(row&7) (swizzle)
    const int r0 = tid >> 3;                       // 0..31
    const int cs = (tid & 7) ^ (r0 & 7);
    const u16* gA = A + (size_t)(m0 + r0) * K + cs * 8;
    const u16* gB = Bw + (size_t)(n0 + r0) * K + cs * 8;

    const int swzf = l16 & 7;                      // fragment-read swizzle (row&7)

    f32x4 acc[4][4];
#pragma unroll
    for (int i = 0; i < 4; i++)
#pragma unroll
        for (int j = 0; j < 4; j++) acc[i][j] = {0.f, 0.f, 0.f, 0.f};

    for (int k0 = 0; k0 < K; k0 += 64) {
        __syncthreads();
#pragma unroll
        for (int j = 0; j < 4; j++) {
            __builtin_amdgcn_global_load_lds((gas_p)(gA + k0 + (size_t)(j * 32) * K),
                                             (las_p)(smA + j * 2048 + tid * 8), 16, 0, 0);
            __builtin_amdgcn_global_load_lds((gas_p)(gB + k0 + (size_t)(j * 32) * K),
                                             (las_p)(smB + j * 2048 + tid * 8), 16, 0, 0);
        }
        __syncthreads();
#pragma unroll
        for (int seg = 0; seg < 2; seg++) {
            bf16x8 af[4], bfv[4];
#pragma unroll
            for (int mi = 0; mi < 4; mi++)
                af[mi] = *(const bf16x8*)&smA[(wr * 64 + mi * 16 + l16) * 64 +
                                              (((seg * 4 + quad) ^ swzf) * 8)];
#pragma unroll
            for (int ni = 0; ni < 4; ni++)
                bfv[ni] = *(const bf16x8*)&smB[(wc * 64 + ni * 16 + l16) * 64 +
                                               (((seg * 4 + quad) ^ swzf) * 8)];
#pragma unroll
            for (int mi = 0; mi < 4; mi++)
#pragma unroll
                for (int ni = 0; ni < 4; ni++)
                    acc[mi][ni] = __builtin_amdgcn_mfma_f32_16x16x32_bf16(
                        af[mi], bfv[ni], acc[mi][ni], 0, 0, 0);
        }
    }

    if constexpr (MODE == 5) {
        // phase 1: dump C-tile (bf16) into the contiguous 32 KB LDS at smA
        u16* smC = smA;
        __syncthreads();
#pragma unroll
        for (int mi = 0; mi < 4; mi++)
#pragma unroll
            for (int ni = 0; ni < 4; ni++) {
                const int lr = wr * 64 + mi * 16 + quad * 4;
                const int lc = wc * 64 + ni * 16 + l16;
#pragma unroll
                for (int r = 0; r < 4; r++)
                    smC[(lr + r) * 128 + lc] = f2bf(acc[mi][ni][r]);
            }
        __syncthreads();
        // phase 2: row-major vectorized epilogue; thread t -> rows (t>>4)+16k, cols (t&15)*8..+7
        const float os = oscp[0];
        const int tr = tid >> 4, tc = tid & 15;
        u16* ob = (u16*)Cout;
#pragma unroll
        for (int rb = 0; rb < 8; rb++) {
            const int row = rb * 16 + tr;
            const int gm = m0 + row;
            const int gn0 = n0 + tc * 8;
            const u16* zr = Zf + (size_t)gm * NZz;
            const float* xr = xres + (size_t)gm * Dd;
            float4 xv0 = *(const float4*)(xr + gn0);
            float4 xv1 = *(const float4*)(xr + gn0 + 4);
            ushort4 c0 = *(const ushort4*)(zr + gn0);
            ushort4 c1 = *(const ushort4*)(zr + gn0 + 4);
            ushort4 g0 = *(const ushort4*)(zr + 1024 + gn0);
            ushort4 g1 = *(const ushort4*)(zr + 1024 + gn0 + 4);
            ushort4 a0 = *(const ushort4*)(zr + 2560 + gn0);
            ushort4 a1 = *(const ushort4*)(zr + 2560 + gn0 + 4);
            const u16* pp = &smC[row * 128 + tc * 8];
            float s1 = 0.f, s2 = 0.f;
            ushort4 o0, o1;
#pragma unroll
            for (int j = 0; j < 4; j++) {
                float p = bf2f(pp[j]);
                float v = (&xv0.x)[j] + 0.5f * (p * os * sigm(bf2f((&a0.x)[j])) +
                                                bf2f((&c0.x)[j]) * sigm(bf2f((&g0.x)[j])));
                s1 += v; s2 += v * v;
                (&o0.x)[j] = f2bf(v);
            }
#pragma unroll
            for (int j = 0; j < 4; j++) {
                float p = bf2f(pp[4 + j]);
                float v = (&xv1.x)[j] + 0.5f * (p * os * sigm(bf2f((&a1.x)[j])) +
                                                bf2f((&c1.x)[j]) * sigm(bf2f((&g1.x)[j])));
                s1 += v; s2 += v * v;
                (&o1.x)[j] = f2bf(v);
            }
            *(ushort4*)(ob + (size_t)gm * Dd + gn0)     = o0;
            *(ushort4*)(ob + (size_t)gm * Dd + gn0 + 4) = o1;
            // reduce across the 16 tc-lanes (same row)
#pragma unroll
            for (int o = 1; o < 16; o <<= 1) {
                s1 += __shfl_xor(s1, o); s2 += __shfl_xor(s2, o);
            }
            if (tc == 0) psums[(size_t)(n0 >> 7) * Mm + gm] = f32x2{s1, s2};
        }
        return;
    }

    if constexpr (MODE == 3) {
        // two-pass f32 LDS transpose (row halves); smA..=u16[16896] -> f32[64][132] (33792 B)
        float* smF = (float*)smA;
#pragma unroll
        for (int h = 0; h < 2; h++) {
            __syncthreads();
            if (wr == h) {
#pragma unroll
                for (int mi = 0; mi < 4; mi++)
#pragma unroll
                    for (int ni = 0; ni < 4; ni++) {
                        const int lr = mi * 16 + quad * 4;
                        const int lc = wc * 64 + ni * 16 + l16;
#pragma unroll
                        for (int r = 0; r < 4; r++)
                            smF[(lr + r) * 132 + lc] = acc[mi][ni][r];
                    }
            }
            __syncthreads();
            const int tr = tid >> 4, tc = tid & 15;
#pragma unroll
            for (int rb = 0; rb < 4; rb++) {
                const int lrow = rb * 16 + tr;
                const int gm = m0 + h * 64 + lrow;
                const int gn0 = n0 + tc * 8;
                f32x4 p0 = *(const f32x4*)&smF[lrow * 132 + tc * 8];
                f32x4 p1 = *(const f32x4*)&smF[lrow * 132 + tc * 8 + 4];
                float4 bv0 = *(const float4*)(bias + gn0);
                float4 bv1 = *(const float4*)(bias + gn0 + 4);
                ushort4 ab0 = *(const ushort4*)(addb + (size_t)gm * N + gn0);
                ushort4 ab1 = *(const ushort4*)(addb + (size_t)gm * N + gn0 + 4);
                float4 o0, o1;
                o0.x = p0[0] + bv0.x + bf2f(ab0.x);
                o0.y = p0[1] + bv0.y + bf2f(ab0.y);
                o0.z = p0[2] + bv0.z + bf2f(ab0.z);
                o0.w = p0[3] + bv0.w + bf2f(ab0.w);
                o1.x = p1[0] + bv1.x + bf2f(ab1.x);
                o1.y = p1[1] + bv1.y + bf2f(ab1.y);
                o1.z = p1[2] + bv1.z + bf2f(ab1.z);
                o1.w = p1[3] + bv1.w + bf2f(ab1.w);
                *(float4*)((float*)Cout + (size_t)gm * N + gn0)     = o0;
                *(float4*)((float*)Cout + (size_t)gm * N + gn0 + 4) = o1;
            }
        }
        return;
    }

#pragma unroll
    for (int mi = 0; mi < 4; mi++) {
#pragma unroll
        for (int ni = 0; ni < 4; ni++) {
            const int gn = n0 + wc * 64 + ni * 16 + l16;
            const int gm0 = m0 + wr * 64 + mi * 16 + quad * 4;
            float bv = (MODE == 4) ? 0.0f : bias[gn];
            float t0 = acc[mi][ni][0] + bv, t1 = acc[mi][ni][1] + bv;
            float t2 = acc[mi][ni][2] + bv, t3 = acc[mi][ni][3] + bv;
            if constexpr (MODE == 2) {
                t0 = gelu_ex(t0); t1 = gelu_ex(t1); t2 = gelu_ex(t2); t3 = gelu_ex(t3);
            }
            __hip_bfloat162 h01 = __float22bfloat162_rn(float2{t0, t1});
            __hip_bfloat162 h23 = __float22bfloat162_rn(float2{t2, t3});
            __hip_bfloat16* o = (__hip_bfloat16*)Cout;
            o[(size_t)(gm0 + 0) * N + gn] = h01.x;
            o[(size_t)(gm0 + 1) * N + gn] = h01.y;
            o[(size_t)(gm0 + 2) * N + gn] = h23.x;
            o[(size_t)(gm0 + 3) * N + gn] = h23.y;
        }
    }
}

template<int MODE>
__global__ __launch_bounds__(256, 3) void gemm_bt(
    const u16* __restrict__ A, const u16* __restrict__ Bw,
    const float* __restrict__ bias, const u16* __restrict__ addb,
    void* __restrict__ Cout, int M, int N, int K)
{
    // MODE 3 needs 33792 B contiguous (f32[64][132]); others 32 KB (smA|smB)
    __shared__ __align__(16) u16 smX[MODE == 3 ? 16896 : 16384];
    gemm_body<MODE>(blockIdx.x * 128, blockIdx.y * 128, smX, smX + 128 * 64,
                    A, Bw, bias, addb, Cout, M, N, K);
}

// fat step-2 kernel: gemm blocks first (1D linearized, x-major like the 2D grid),
// then deferred wfs/w1/w2 conversion blocks fill CU slots as gemm blocks retire.
static constexpr int NG2 = (Mm / 128) * (NZz / 128);   // 2368 gemm blocks, gx=64
__global__ __launch_bounds__(256, 3) void gemm_cvt0(
    const u16* __restrict__ A, const u16* __restrict__ Bw,
    const float* __restrict__ bias, void* __restrict__ Cout,
    int M, int N, int K,
    const float* __restrict__ Wfs, const float* __restrict__ W1,
    const float* __restrict__ W2,
    u16* __restrict__ wfs, u16* __restrict__ w1b, u16* __restrict__ w2b)
{
    const int bid = blockIdx.x;
    if (bid < NG2) {
        __shared__ __align__(16) u16 smA[128 * 64];
        __shared__ __align__(16) u16 smB[128 * 64];
        gemm_body<0>((bid & 63) * 128, (bid >> 6) * 128, smA, smB,
                     A, Bw, bias, nullptr, Cout, M, N, K);
        return;
    }
    const int i = (bid - NG2) * 1024 + threadIdx.x * 4;
    if (i < NW1) {
        float4 v = *(const float4*)(Wfs + i);
        *(ushort4*)(wfs + i) = ushort4{f2bf(v.x), f2bf(v.y), f2bf(v.z), f2bf(v.w)};
    } else if (i < NW1 + NW2) {
        int j = i - NW1;
        float4 v = *(const float4*)(W1 + j);
        *(ushort4*)(w1b + j) = ushort4{f2bf(v.x), f2bf(v.y), f2bf(v.z), f2bf(v.w)};
    } else {
        int j = i - NW1 - NW2;
        float4 v = *(const float4*)(W2 + j);
        *(ushort4*)(w2b + j) = ushort4{f2bf(v.x), f2bf(v.y), f2bf(v.z), f2bf(v.w)};
    }
}

// gemm5 with fused fuse2 epilogue (MODE 5). Contiguous 32 KB LDS for the C-transpose.
__global__ __launch_bounds__(256, 3) void gemm5_fuse(
    const u16* __restrict__ A, const u16* __restrict__ Bw,
    void* __restrict__ Cout, int M, int N, int K,
    const float* __restrict__ xres, const u16* __restrict__ Zf,
    const float* __restrict__ oscp, f32x2* __restrict__ psums)
{
    __shared__ __align__(16) u16 smX[128 * 128];   // 32 KB contiguous
    gemm_body<5>(blockIdx.x * 128, blockIdx.y * 128, smX, smX + 128 * 64,
                 A, Bw, nullptr, nullptr, Cout, M, N, K,
                 xres, Zf, oscp, psums);
}

// ---------------------------------------------------------------- ln2_finish: xn2 = LN(x2b) from partial sums
__global__ __launch_bounds__(256) void ln2_finish(
    const f32x2* __restrict__ psums, const u16* __restrict__ x2b,
    const float* __restrict__ g2, const float* __restrict__ b2v,
    u16* __restrict__ xn2)
{
    const int m = blockIdx.x, tid = threadIdx.x;
    __shared__ float sm[2];
    if (tid < 64) {
        f32x2 p = (tid < 8) ? psums[(size_t)tid * Mm + m] : f32x2{0.f, 0.f};
        for (int o = 4; o; o >>= 1) { p.x += __shfl_down(p.x, o); p.y += __shfl_down(p.y, o); }
        if (tid == 0) { sm[0] = p.x; sm[1] = p.y; }
    }
    __syncthreads();
    float mean = sm[0] * (1.0f / Dd);
    float var  = sm[1] * (1.0f / Dd) - mean * mean;
    float rstd = rsqrtf(var + 1e-5f);
    ushort4 h = ((const ushort4*)(x2b + (size_t)m * Dd))[tid];
    float4 gv = ((const float4*)g2)[tid];
    float4 bv = ((const float4*)b2v)[tid];
    ushort4 o;
    o.x = f2bf((bf2f(h.x) - mean) * rstd * gv.x + bv.x);
    o.y = f2bf((bf2f(h.y) - mean) * rstd * gv.y + bv.y);
    o.z = f2bf((bf2f(h.z) - mean) * rstd * gv.z + bv.z);
    o.w = f2bf((bf2f(h.w) - mean) * rstd * gv.w + bv.w);
    ((ushort4*)(xn2 + (size_t)m * Dd))[tid] = o;
}

// ---------------------------------------------------------------- conv: u from Z on the fly; in-kernel k recurrence
// rotating register window (no shift movs): win[(j - tau) & 15] holds u[tl0 + j - tau]
__global__ __launch_bounds__(256) void conv_kernel(
    const u16* __restrict__ Z,
    const float* __restrict__ Ar, const float* __restrict__ Ai,
    const float* __restrict__ rr, const float* __restrict__ ri,
    u16* __restrict__ spec)
{
    __shared__ ushort2 su[96 * 64];   // 24.5 KB: u rows t0-32 .. t0+63 (bf16 pair)
    __shared__ float stsv[Lc], sbsv[Lc];
    const int tid = threadIdx.x;
    const int fl = tid & 63;
    const int ty = tid >> 6;          // 0..3
    const int f0 = blockIdx.x * 64;
    const int t0 = blockIdx.y * 64;
    const int b  = blockIdx.z;
    const int band = f0 >> 7;         // uniform within a 64-freq block

    // stage lane-uniform temporal/band strengths for the 32 taps
    if (tid < Lc) {
        stsv[tid] = sigm(bf2f(Z[(size_t)(b * Tt + tid) * NZz + 4608]));
    } else if (tid < 2 * Lc) {
        int tau = tid - Lc;
        sbsv[tau] = sigm(bf2f(Z[(size_t)(b * Tt + tau) * NZz + 4609 + band]));
    }
    // stage u = sp * sigmoid(fg) rows (bf16); 2 freqs per thread, vectorized
    for (int i = tid; i < 96 * 32; i += 256) {
        int r = i >> 5, fp = (i & 31) * 2;
        int t = t0 - 32 + r;
        ushort4 v{0, 0, 0, 0};
        if (t >= 0) {
            const u16* zr = Z + (size_t)(b * Tt + t) * NZz;
            ushort2 fg2 = *(const ushort2*)(zr + 2048 + f0 + fp);
            ushort2 sr2 = *(const ushort2*)(zr + 3584 + f0 + fp);
            ushort2 si2 = *(const ushort2*)(zr + 4096 + f0 + fp);
            float g0 = sigm(bf2f(fg2.x)), g1 = sigm(bf2f(fg2.y));
            v.x = f2bf(bf2f(sr2.x) * g0); v.y = f2bf(bf2f(si2.x) * g0);
            v.z = f2bf(bf2f(sr2.y) * g1); v.w = f2bf(bf2f(si2.y) * g1);
        }
        *(ushort4*)&su[r * 64 + fp] = v;
    }
    __syncthreads();

    // per-lane recurrence state for freq f0+fl
    const float ar = Ar[f0 + fl], ai = Ai[f0 + fl];
    const float cr = rr[f0 + fl], ci = ri[f0 + fl];
    float Pr = 1.0f, Pi = 0.0f;

    const int tl0 = 32 + ty * 16;
    f32x2 win[16], y[16];
#pragma unroll
    for (int j = 0; j < 16; j++) {
        ushort2 h = su[(tl0 + j) * 64 + fl];
        win[j] = f32x2{bf2f(h.x), bf2f(h.y)};
        y[j] = f32x2{0.f, 0.f};
    }
#pragma unroll
    for (int tau = 0; tau < Lc; tau++) {
        float tsv = stsv[tau];
        float kr = tsv * (cr * Pr - ci * Pi);
        float ki = tsv * (cr * Pi + ci * Pr);
#pragma unroll
        for (int j = 0; j < 16; j++) {
            const int s = (j - tau) & 15;          // compile-time after unroll
            y[j].x += win[s].x * kr - win[s].y * ki;
            y[j].y += win[s].x * ki + win[s].y * kr;
        }
        {
            const int s0 = (15 - tau) & 15;        // slot that just expired
            ushort2 h = su[(tl0 - tau - 1) * 64 + fl];   // >= row 0 always
            win[s0] = f32x2{bf2f(h.x), bf2f(h.y)};
        }
        float bsv = sbsv[tau];
        float er = ar * bsv, ei = ai * bsv;
        float nPr = Pr * er - Pi * ei;
        float nPi = Pr * ei + Pi * er;
        Pr = nPr; Pi = nPi;
    }
#pragma unroll
    for (int j = 0; j < 16; j++) {
        size_t row = (size_t)(b * Tt + t0 + ty * 16 + j);
        spec[row * (2 * NFf) + f0 + fl]       = f2bf(y[j].x);
        spec[row * (2 * NFf) + NFf + f0 + fl] = f2bf(y[j].y);
    }
}

// ---------------------------------------------------------------- launch
extern "C" void kernel_launch(void* const* d_in, const int* in_sizes, int n_in,
                              void* d_out, int out_size, void* d_ws, size_t ws_size,
                              hipStream_t stream)
{
    const float* x        = (const float*)d_in[0];
    const float* norm_g   = (const float*)d_in[1];
    const float* norm_b   = (const float*)d_in[2];
    const float* Wconcept = (const float*)d_in[3];
    const float* bconcept = (const float*)d_in[4];
    const float* Wcg      = (const float*)d_in[5];
    const float* bcg      = (const float*)d_in[6];
    const float* Wfg      = (const float*)d_in[7];
    const float* bfg      = (const float*)d_in[8];
    const float* Wtg      = (const float*)d_in[9];
    const float* btg      = (const float*)d_in[10];
    const float* Wband    = (const float*)d_in[11];
    const float* bband    = (const float*)d_in[12];
    const float* Wsp      = (const float*)d_in[13];
    const float* fi       = (const float*)d_in[14];
    const float* logd     = (const float*)d_in[15];
    const float* freqs    = (const float*)d_in[16];
    const float* dtv      = (const float*)d_in[17];
    const float* Wgate    = (const float*)d_in[18];
    const float* bgate    = (const float*)d_in[19];
    const float* Wfs      = (const float*)d_in[20];
    const float* osc      = (const float*)d_in[21];
    const float* n2g      = (const float*)d_in[22];
    const float* n2b      = (const float*)d_in[23];
    const float* W1       = (const float*)d_in[24];
    const float* b1       = (const float*)d_in[25];
    const float* W2       = (const float*)d_in[26];
    const float* b2       = (const float*)d_in[27];

    char* ws = (char*)d_ws;
    size_t off = 0;
    auto alloc = [&](size_t bytes) { size_t c = off; off += (bytes + 255) & ~(size_t)255; return c; };
    size_t o_wcat = alloc((size_t)NZz * Dd * 2);
    size_t o_bias = alloc((size_t)NZz * 4);
    size_t o_wfs  = alloc((size_t)Dd * 2 * NFf * 2);
    size_t o_w1   = alloc((size_t)4 * Dd * Dd * 2);
    size_t o_w2   = alloc((size_t)4 * Dd * Dd * 2);
    size_t o_xn   = alloc((size_t)Mm * Dd * 2);
    size_t o_Z    = alloc((size_t)Mm * NZz * 2);        // reused for h
    size_t o_u    = alloc((size_t)Mm * NFf * 4);        // x2b (bf16)
    size_t o_spec = alloc((size_t)Mm * Dd * 2);         // spectral; later xn2
    size_t o_ps   = alloc((size_t)8 * Mm * 8);          // LN2 partial sums (f32x2)
    size_t o_rr   = alloc(NFf * 4);
    size_t o_ri   = alloc(NFf * 4);
    size_t o_Ar   = alloc(NFf * 4);
    size_t o_Ai   = alloc(NFf * 4);
    if (ws_size < off) return;

    u16*    wcat = (u16*)(ws + o_wcat);
    float*  bias = (float*)(ws + o_bias);
    u16*    wfs  = (u16*)(ws + o_wfs);
    u16*    w1b  = (u16*)(ws + o_w1);
    u16*    w2b  = (u16*)(ws + o_w2);
    u16*    xn   = (u16*)(ws + o_xn);
    u16*    Zb   = (u16*)(ws + o_Z);
    u16*    hb   = (u16*)(ws + o_Z);
    u16*    x2b  = (u16*)(ws + o_u);
    u16*    spec = (u16*)(ws + o_spec);
    u16*    xn2  = (u16*)(ws + o_spec);
    f32x2*  psums = (f32x2*)(ws + o_ps);
    float*  rr   = (float*)(ws + o_rr);
    float*  ri   = (float*)(ws + o_ri);
    float*  Ar   = (float*)(ws + o_Ar);
    float*  Ai   = (float*)(ws + o_Ai);

    // 1) freq consts + wcat conversion + LN1
    prep_all<<<1 + NWB_CAT + Mm, 256, 0, stream>>>(
        Wconcept, Wcg, Wfg, Wgate, Wsp, Wtg, Wband,
        bconcept, bcg, bfg, bgate, btg, bband,
        fi, logd, freqs, dtv,
        x, norm_g, norm_b,
        wcat, bias, rr, ri, Ar, Ai, xn);

    // 2) fused projection GEMM (Z = xn @ wcat^T + bias) + wfs/w1/w2 conversion
    gemm_cvt0<<<NG2 + NCVT, 256, 0, stream>>>(
        xn, wcat, bias, (void*)Zb, Mm, NZz, Dd,
        Wfs, W1, W2, wfs, w1b, w2b);

    // 3) truncated causal convolution (u from Z on the fly, in-kernel k recurrence)
    conv_kernel<<<dim3(NFf / 64, Tt / 64, Bb), 256, 0, stream>>>(
        Zb, Ar, Ai, rr, ri, spec);

    // 4) P2-GEMM with fused fuse2 epilogue (x2b + LN2 partial sums); P2 never hits HBM
    gemm5_fuse<<<dim3(Mm / 128, Dd / 128), 256, 0, stream>>>(
        spec, wfs, (void*)x2b, Mm, Dd, 2 * NFf,
        x, Zb, osc, psums);

    // 5) LN2 finish: xn2 = LN(x2b) using partial sums
    ln2_finish<<<Mm, 256, 0, stream>>>(psums, x2b, n2g, n2b, xn2);

    // 6) MLP
    gemm_bt<2><<<dim3(Mm / 128, (4 * Dd) / 128), 256, 0, stream>>>(
        xn2, w1b, b1, nullptr, (void*)hb, Mm, 4 * Dd, Dd);
    gemm_bt<3><<<dim3(Mm / 128, Dd / 128), 256, 0, stream>>>(
        hb, w2b, b2, x2b, d_out, Mm, Dd, 4 * Dd);
}

// Round 8
// 497.892 us; speedup vs baseline: 1.0174x; 1.0174x over previous
//
#include <hip/hip_runtime.h>
#include <hip/hip_bf16.h>
#include <cstdint>
#include <cstddef>

typedef unsigned short u16;
typedef unsigned int u32;
typedef short bf16x8 __attribute__((ext_vector_type(8)));
typedef float f32x4 __attribute__((ext_vector_type(4)));
typedef float f32x2 __attribute__((ext_vector_type(2)));

static constexpr int Bb = 4, Tt = 2048, Dd = 1024, NFf = 512, NBb = 4;
static constexpr int Mm = Bb * Tt;      // 8192 tokens
static constexpr int NZz = 4736;        // packed projection width (4613 padded to 37*128)
static constexpr int Lc = 32;           // conv kernel support (|A|<=0.59 -> 0.59^32 ~ 5e-8)

#define DEV __device__ __forceinline__

typedef const __attribute__((address_space(1))) u32* gas_p;
typedef __attribute__((address_space(3))) u32* las_p;

DEV u16 f2bf(float f) {
    uint32_t u = __float_as_uint(f);
    u = (u + 0x7FFF + ((u >> 16) & 1)) >> 16;   // RNE
    return (u16)u;
}
DEV float bf2f(u16 h) { return __uint_as_float(((uint32_t)h) << 16); }
DEV float sigm(float x) { return 1.0f / (1.0f + __expf(-x)); }
DEV float gelu_ex(float t) { return 0.5f * t * (1.0f + erff(t * 0.70710678118f)); }

// ---------------------------------------------------------------- sizes
static constexpr int NW0 = NZz * Dd;        // wcat elements
static constexpr int NW1 = Dd * 2 * NFf;    // wfs
static constexpr int NW2 = 4 * Dd * Dd;     // w1
static constexpr int NW3 = 4 * Dd * Dd;     // w2
static constexpr int NWB_CAT = NW0 / 1024;  // wcat convert blocks (float4 per thread)
static constexpr int NCVT = (NW1 + NW2 + NW3) / 1024;   // 9216 deferred convert blocks

// ---------------------------------------------------------------- prep_all: freq consts + wcat cvt + LN1
__global__ __launch_bounds__(256) void prep_all(
    const float* __restrict__ Wconcept, const float* __restrict__ Wcg,
    const float* __restrict__ Wfg, const float* __restrict__ Wgate,
    const float* __restrict__ Wsp, const float* __restrict__ Wtg,
    const float* __restrict__ Wband,
    const float* __restrict__ bconcept, const float* __restrict__ bcg,
    const float* __restrict__ bfg, const float* __restrict__ bgate,
    const float* __restrict__ btg, const float* __restrict__ bband,
    const float* __restrict__ fi, const float* __restrict__ logd,
    const float* __restrict__ freqs, const float* __restrict__ dtv,
    const float* __restrict__ x, const float* __restrict__ norm_g,
    const float* __restrict__ norm_b,
    u16* __restrict__ wcat, float* __restrict__ bias_cat,
    float* __restrict__ rr, float* __restrict__ ri,
    float* __restrict__ Ar, float* __restrict__ Ai,
    u16* __restrict__ xn)
{
    const int bx = blockIdx.x;
    if (bx == 0) {
        __shared__ float red[256];
        int t = threadIdx.x;
        float v0 = fi[t], v1 = fi[t + 256];
        red[t] = fmaxf(v0, v1); __syncthreads();
        for (int s = 128; s; s >>= 1) { if (t < s) red[t] = fmaxf(red[t], red[t + s]); __syncthreads(); }
        float mx = red[0]; __syncthreads();
        float e0 = expf(v0 - mx), e1 = expf(v1 - mx);
        red[t] = e0 + e1; __syncthreads();
        for (int s = 128; s; s >>= 1) { if (t < s) red[t] += red[t + s]; __syncthreads(); }
        float inv = 1.0f / red[0];
#pragma unroll
        for (int k = 0; k < 2; k++) {
            int f = t + k * 256;
            float e = k ? e1 : e0;
            float decay = sigm(logd[f]) * (e * inv * (float)NFf);
            float omega = freqs[f] * 0.1f * (sigm(dtv[f]) * 2.0f);
            float cc = cosf(omega), ss = sinf(omega);
            rr[f] = cc; ri[f] = ss; Ar[f] = decay * cc; Ai[f] = decay * ss;
        }
        return;
    }
    if (bx <= NWB_CAT) {
        const int i = ((bx - 1) * 256 + threadIdx.x) * 4;   // 4 consecutive elements of wcat
        int r = i >> 10, c = i & 1023;
        float4 v = {0.f, 0.f, 0.f, 0.f};
        if      (r < 1024) v = *(const float4*)(Wconcept + r * 1024 + c);
        else if (r < 2048) v = *(const float4*)(Wcg + (r - 1024) * 1024 + c);
        else if (r < 2560) v = *(const float4*)(Wfg + (r - 2048) * 1024 + c);
        else if (r < 3584) v = *(const float4*)(Wgate + (r - 2560) * 1024 + c);
        else if (r < 4608) v = *(const float4*)(Wsp + (r - 3584) * 1024 + c);
        else if (r == 4608) v = *(const float4*)(Wtg + c);
        else if (r < 4613) v = *(const float4*)(Wband + (r - 4609) * 1024 + c);
        *(ushort4*)(wcat + i) = ushort4{f2bf(v.x), f2bf(v.y), f2bf(v.z), f2bf(v.w)};
        if (c == 0) {
            float bv;
            if      (r < 1024) bv = bconcept[r];
            else if (r < 2048) bv = bcg[r - 1024];
            else if (r < 2560) bv = bfg[r - 2048];
            else if (r < 3584) bv = bgate[r - 2560];
            else if (r < 4608) bv = 0.0f;
            else if (r == 4608) bv = btg[0];
            else if (r < 4613) bv = bband[r - 4609];
            else bv = 0.0f;
            bias_cat[r] = bv;
        }
        return;
    }
    // LN1 role: one block per token row
    const int m = bx - NWB_CAT - 1, tid = threadIdx.x;
    float4 v = ((const float4*)(x + (size_t)m * Dd))[tid];
    float s1 = v.x + v.y + v.z + v.w;
    float s2 = v.x * v.x + v.y * v.y + v.z * v.z + v.w * v.w;
    __shared__ float lds[16];
    for (int o = 32; o; o >>= 1) { s1 += __shfl_down(s1, o); s2 += __shfl_down(s2, o); }
    int lane = tid & 63, w = tid >> 6;
    if (!lane) { lds[w] = s1; lds[8 + w] = s2; }
    __syncthreads();
    s1 = lds[0] + lds[1] + lds[2] + lds[3];
    s2 = lds[8] + lds[9] + lds[10] + lds[11];
    float mean = s1 * (1.0f / Dd);
    float var  = s2 * (1.0f / Dd) - mean * mean;
    float rstd = rsqrtf(var + 1e-5f);
    float4 gv = ((const float4*)norm_g)[tid];
    float4 bv = ((const float4*)norm_b)[tid];
    ushort4 o;
    o.x = f2bf((v.x - mean) * rstd * gv.x + bv.x);
    o.y = f2bf((v.y - mean) * rstd * gv.y + bv.y);
    o.z = f2bf((v.z - mean) * rstd * gv.z + bv.z);
    o.w = f2bf((v.w - mean) * rstd * gv.w + bv.w);
    ((ushort4*)(xn + (size_t)m * Dd))[tid] = o;
}

// ---------------------------------------------------------------- GEMM body (bf16 MFMA, BK=64, xor-swizzled LDS)
// MODE 0: bf16 = acc + bias[n]   MODE 2: bf16 = gelu(acc+bias)   MODE 4: bf16 = acc
// MODE 3: f32 = acc + bias[n] + bf2f(addb[m,n])
// MODE 5: fuse2 epilogue via LDS transpose (smA MUST be a contiguous 32 KB [128][128] buffer
//         with smB = smA + 128*64): bf16 C-tile -> LDS -> row-major vectorized pass:
//         v = x + 0.5*(p*os*gate + concept*cg); bf16 x2b out + per-(row,tile) psums for LN2
template<int MODE>
DEV void gemm_body(int m0, int n0,
                   u16* __restrict__ smA, u16* __restrict__ smB,
                   const u16* __restrict__ A, const u16* __restrict__ Bw,
                   const float* __restrict__ bias, const u16* __restrict__ addb,
                   void* __restrict__ Cout, int M, int N, int K,
                   const float* __restrict__ xres = nullptr,
                   const u16* __restrict__ Zf = nullptr,
                   const float* __restrict__ oscp = nullptr,
                   f32x2* __restrict__ psums = nullptr)
{
    const int tid = threadIdx.x;
    const int w = tid >> 6, lane = tid & 63;
    const int wr = w >> 1, wc = w & 1;
    const int quad = lane >> 4, l16 = lane & 15;

    // staging: thread t -> tile row (t>>3) + 32*j; global chunk (t&7)^(row&7) (swizzle)
    const int r0 = tid >> 3;                       // 0..31
    const int cs = (tid & 7) ^ (r0 & 7);
    const u16* gA = A + (size_t)(m0 + r0) * K + cs * 8;
    const u16* gB = Bw + (size_t)(n0 + r0) * K + cs * 8;

    const int swzf = l16 & 7;                      // fragment-read swizzle (row&7)

    f32x4 acc[4][4];
#pragma unroll
    for (int i = 0; i < 4; i++)
#pragma unroll
        for (int j = 0; j < 4; j++) acc[i][j] = {0.f, 0.f, 0.f, 0.f};

    for (int k0 = 0; k0 < K; k0 += 64) {
        __syncthreads();
#pragma unroll
        for (int j = 0; j < 4; j++) {
            __builtin_amdgcn_global_load_lds((gas_p)(gA + k0 + (size_t)(j * 32) * K),
                                             (las_p)(smA + j * 2048 + tid * 8), 16, 0, 0);
            __builtin_amdgcn_global_load_lds((gas_p)(gB + k0 + (size_t)(j * 32) * K),
                                             (las_p)(smB + j * 2048 + tid * 8), 16, 0, 0);
        }
        __syncthreads();
#pragma unroll
        for (int seg = 0; seg < 2; seg++) {
            bf16x8 af[4], bfv[4];
#pragma unroll
            for (int mi = 0; mi < 4; mi++)
                af[mi] = *(const bf16x8*)&smA[(wr * 64 + mi * 16 + l16) * 64 +
                                              (((seg * 4 + quad) ^ swzf) * 8)];
#pragma unroll
            for (int ni = 0; ni < 4; ni++)
                bfv[ni] = *(const bf16x8*)&smB[(wc * 64 + ni * 16 + l16) * 64 +
                                               (((seg * 4 + quad) ^ swzf) * 8)];
#pragma unroll
            for (int mi = 0; mi < 4; mi++)
#pragma unroll
                for (int ni = 0; ni < 4; ni++)
                    acc[mi][ni] = __builtin_amdgcn_mfma_f32_16x16x32_bf16(
                        af[mi], bfv[ni], acc[mi][ni], 0, 0, 0);
        }
    }

    if constexpr (MODE == 5) {
        // phase 1: dump C-tile (bf16) into the contiguous 32 KB LDS at smA
        u16* smC = smA;
        __syncthreads();
#pragma unroll
        for (int mi = 0; mi < 4; mi++)
#pragma unroll
            for (int ni = 0; ni < 4; ni++) {
                const int lr = wr * 64 + mi * 16 + quad * 4;
                const int lc = wc * 64 + ni * 16 + l16;
#pragma unroll
                for (int r = 0; r < 4; r++)
                    smC[(lr + r) * 128 + lc] = f2bf(acc[mi][ni][r]);
            }
        __syncthreads();
        // phase 2: row-major vectorized epilogue; thread t -> rows (t>>4)+16k, cols (t&15)*8..+7
        const float os = oscp[0];
        const int tr = tid >> 4, tc = tid & 15;
        u16* ob = (u16*)Cout;
#pragma unroll
        for (int rb = 0; rb < 8; rb++) {
            const int row = rb * 16 + tr;
            const int gm = m0 + row;
            const int gn0 = n0 + tc * 8;
            const u16* zr = Zf + (size_t)gm * NZz;
            const float* xr = xres + (size_t)gm * Dd;
            float4 xv0 = *(const float4*)(xr + gn0);
            float4 xv1 = *(const float4*)(xr + gn0 + 4);
            ushort4 c0 = *(const ushort4*)(zr + gn0);
            ushort4 c1 = *(const ushort4*)(zr + gn0 + 4);
            ushort4 g0 = *(const ushort4*)(zr + 1024 + gn0);
            ushort4 g1 = *(const ushort4*)(zr + 1024 + gn0 + 4);
            ushort4 a0 = *(const ushort4*)(zr + 2560 + gn0);
            ushort4 a1 = *(const ushort4*)(zr + 2560 + gn0 + 4);
            const u16* pp = &smC[row * 128 + tc * 8];
            float s1 = 0.f, s2 = 0.f;
            ushort4 o0, o1;
#pragma unroll
            for (int j = 0; j < 4; j++) {
                float p = bf2f(pp[j]);
                float v = (&xv0.x)[j] + 0.5f * (p * os * sigm(bf2f((&a0.x)[j])) +
                                                bf2f((&c0.x)[j]) * sigm(bf2f((&g0.x)[j])));
                s1 += v; s2 += v * v;
                (&o0.x)[j] = f2bf(v);
            }
#pragma unroll
            for (int j = 0; j < 4; j++) {
                float p = bf2f(pp[4 + j]);
                float v = (&xv1.x)[j] + 0.5f * (p * os * sigm(bf2f((&a1.x)[j])) +
                                                bf2f((&c1.x)[j]) * sigm(bf2f((&g1.x)[j])));
                s1 += v; s2 += v * v;
                (&o1.x)[j] = f2bf(v);
            }
            *(ushort4*)(ob + (size_t)gm * Dd + gn0)     = o0;
            *(ushort4*)(ob + (size_t)gm * Dd + gn0 + 4) = o1;
            // reduce across the 16 tc-lanes (same row)
#pragma unroll
            for (int o = 1; o < 16; o <<= 1) {
                s1 += __shfl_xor(s1, o); s2 += __shfl_xor(s2, o);
            }
            if (tc == 0) psums[(size_t)(n0 >> 7) * Mm + gm] = f32x2{s1, s2};
        }
        return;
    }

#pragma unroll
    for (int mi = 0; mi < 4; mi++) {
#pragma unroll
        for (int ni = 0; ni < 4; ni++) {
            const int gn = n0 + wc * 64 + ni * 16 + l16;
            const int gm0 = m0 + wr * 64 + mi * 16 + quad * 4;
            if constexpr (MODE == 0 || MODE == 2 || MODE == 4) {
                float bv = (MODE == 4) ? 0.0f : bias[gn];
                float t0 = acc[mi][ni][0] + bv, t1 = acc[mi][ni][1] + bv;
                float t2 = acc[mi][ni][2] + bv, t3 = acc[mi][ni][3] + bv;
                if constexpr (MODE == 2) {
                    t0 = gelu_ex(t0); t1 = gelu_ex(t1); t2 = gelu_ex(t2); t3 = gelu_ex(t3);
                }
                __hip_bfloat162 h01 = __float22bfloat162_rn(float2{t0, t1});
                __hip_bfloat162 h23 = __float22bfloat162_rn(float2{t2, t3});
                __hip_bfloat16* o = (__hip_bfloat16*)Cout;
                o[(size_t)(gm0 + 0) * N + gn] = h01.x;
                o[(size_t)(gm0 + 1) * N + gn] = h01.y;
                o[(size_t)(gm0 + 2) * N + gn] = h23.x;
                o[(size_t)(gm0 + 3) * N + gn] = h23.y;
            } else {
#pragma unroll
                for (int r = 0; r < 4; r++) {
                    const int gm = gm0 + r;
                    ((float*)Cout)[(size_t)gm * N + gn] =
                        acc[mi][ni][r] + bias[gn] + bf2f(addb[(size_t)gm * N + gn]);
                }
            }
        }
    }
}

template<int MODE>
__global__ __launch_bounds__(256, 3) void gemm_bt(
    const u16* __restrict__ A, const u16* __restrict__ Bw,
    const float* __restrict__ bias, const u16* __restrict__ addb,
    void* __restrict__ Cout, int M, int N, int K)
{
    __shared__ __align__(16) u16 smA[128 * 64];   // 16 KB
    __shared__ __align__(16) u16 smB[128 * 64];   // 16 KB
    gemm_body<MODE>(blockIdx.x * 128, blockIdx.y * 128, smA, smB,
                    A, Bw, bias, addb, Cout, M, N, K);
}

// fat step-2 kernel: gemm blocks first (1D linearized, x-major like the 2D grid),
// then deferred wfs/w1/w2 conversion blocks fill CU slots as gemm blocks retire.
static constexpr int NG2 = (Mm / 128) * (NZz / 128);   // 2368 gemm blocks, gx=64
__global__ __launch_bounds__(256, 3) void gemm_cvt0(
    const u16* __restrict__ A, const u16* __restrict__ Bw,
    const float* __restrict__ bias, void* __restrict__ Cout,
    int M, int N, int K,
    const float* __restrict__ Wfs, const float* __restrict__ W1,
    const float* __restrict__ W2,
    u16* __restrict__ wfs, u16* __restrict__ w1b, u16* __restrict__ w2b)
{
    const int bid = blockIdx.x;
    if (bid < NG2) {
        __shared__ __align__(16) u16 smA[128 * 64];
        __shared__ __align__(16) u16 smB[128 * 64];
        gemm_body<0>((bid & 63) * 128, (bid >> 6) * 128, smA, smB,
                     A, Bw, bias, nullptr, Cout, M, N, K);
        return;
    }
    const int i = (bid - NG2) * 1024 + threadIdx.x * 4;
    if (i < NW1) {
        float4 v = *(const float4*)(Wfs + i);
        *(ushort4*)(wfs + i) = ushort4{f2bf(v.x), f2bf(v.y), f2bf(v.z), f2bf(v.w)};
    } else if (i < NW1 + NW2) {
        int j = i - NW1;
        float4 v = *(const float4*)(W1 + j);
        *(ushort4*)(w1b + j) = ushort4{f2bf(v.x), f2bf(v.y), f2bf(v.z), f2bf(v.w)};
    } else {
        int j = i - NW1 - NW2;
        float4 v = *(const float4*)(W2 + j);
        *(ushort4*)(w2b + j) = ushort4{f2bf(v.x), f2bf(v.y), f2bf(v.z), f2bf(v.w)};
    }
}

// gemm5 with fused fuse2 epilogue (MODE 5). Contiguous 32 KB LDS for the C-transpose.
__global__ __launch_bounds__(256, 3) void gemm5_fuse(
    const u16* __restrict__ A, const u16* __restrict__ Bw,
    void* __restrict__ Cout, int M, int N, int K,
    const float* __restrict__ xres, const u16* __restrict__ Zf,
    const float* __restrict__ oscp, f32x2* __restrict__ psums)
{
    __shared__ __align__(16) u16 smX[128 * 128];   // 32 KB contiguous
    gemm_body<5>(blockIdx.x * 128, blockIdx.y * 128, smX, smX + 128 * 64,
                 A, Bw, nullptr, nullptr, Cout, M, N, K,
                 xres, Zf, oscp, psums);
}

// ---------------------------------------------------------------- ln2_finish: xn2 = LN(x2b) from partial sums
__global__ __launch_bounds__(256) void ln2_finish(
    const f32x2* __restrict__ psums, const u16* __restrict__ x2b,
    const float* __restrict__ g2, const float* __restrict__ b2v,
    u16* __restrict__ xn2)
{
    const int m = blockIdx.x, tid = threadIdx.x;
    __shared__ float sm[2];
    if (tid < 64) {
        f32x2 p = (tid < 8) ? psums[(size_t)tid * Mm + m] : f32x2{0.f, 0.f};
        for (int o = 4; o; o >>= 1) { p.x += __shfl_down(p.x, o); p.y += __shfl_down(p.y, o); }
        if (tid == 0) { sm[0] = p.x; sm[1] = p.y; }
    }
    __syncthreads();
    float mean = sm[0] * (1.0f / Dd);
    float var  = sm[1] * (1.0f / Dd) - mean * mean;
    float rstd = rsqrtf(var + 1e-5f);
    ushort4 h = ((const ushort4*)(x2b + (size_t)m * Dd))[tid];
    float4 gv = ((const float4*)g2)[tid];
    float4 bv = ((const float4*)b2v)[tid];
    ushort4 o;
    o.x = f2bf((bf2f(h.x) - mean) * rstd * gv.x + bv.x);
    o.y = f2bf((bf2f(h.y) - mean) * rstd * gv.y + bv.y);
    o.z = f2bf((bf2f(h.z) - mean) * rstd * gv.z + bv.z);
    o.w = f2bf((bf2f(h.w) - mean) * rstd * gv.w + bv.w);
    ((ushort4*)(xn2 + (size_t)m * Dd))[tid] = o;
}

// ---------------------------------------------------------------- conv: u from Z on the fly; in-kernel k recurrence
__global__ __launch_bounds__(256) void conv_kernel(
    const u16* __restrict__ Z,
    const float* __restrict__ Ar, const float* __restrict__ Ai,
    const float* __restrict__ rr, const float* __restrict__ ri,
    u16* __restrict__ spec)
{
    __shared__ ushort2 su[96 * 64];   // 24.5 KB: u rows t0-32 .. t0+63 (bf16 pair)
    __shared__ float stsv[Lc], sbsv[Lc];
    const int tid = threadIdx.x;
    const int fl = tid & 63;
    const int ty = tid >> 6;          // 0..3
    const int f0 = blockIdx.x * 64;
    const int t0 = blockIdx.y * 64;
    const int b  = blockIdx.z;
    const int band = f0 >> 7;         // uniform within a 64-freq block

    // stage lane-uniform temporal/band strengths for the 32 taps
    if (tid < Lc) {
        stsv[tid] = sigm(bf2f(Z[(size_t)(b * Tt + tid) * NZz + 4608]));
    } else if (tid < 2 * Lc) {
        int tau = tid - Lc;
        sbsv[tau] = sigm(bf2f(Z[(size_t)(b * Tt + tau) * NZz + 4609 + band]));
    }
    // stage u = sp * sigmoid(fg) rows (bf16); 2 freqs per thread, vectorized
    for (int i = tid; i < 96 * 32; i += 256) {
        int r = i >> 5, fp = (i & 31) * 2;
        int t = t0 - 32 + r;
        ushort4 v{0, 0, 0, 0};
        if (t >= 0) {
            const u16* zr = Z + (size_t)(b * Tt + t) * NZz;
            ushort2 fg2 = *(const ushort2*)(zr + 2048 + f0 + fp);
            ushort2 sr2 = *(const ushort2*)(zr + 3584 + f0 + fp);
            ushort2 si2 = *(const ushort2*)(zr + 4096 + f0 + fp);
            float g0 = sigm(bf2f(fg2.x)), g1 = sigm(bf2f(fg2.y));
            v.x = f2bf(bf2f(sr2.x) * g0); v.y = f2bf(bf2f(si2.x) * g0);
            v.z = f2bf(bf2f(sr2.y) * g1); v.w = f2bf(bf2f(si2.y) * g1);
        }
        *(ushort4*)&su[r * 64 + fp] = v;
    }
    __syncthreads();

    // per-lane recurrence state for freq f0+fl
    const float ar = Ar[f0 + fl], ai = Ai[f0 + fl];
    const float cr = rr[f0 + fl], ci = ri[f0 + fl];
    float Pr = 1.0f, Pi = 0.0f;

    const int tl0 = 32 + ty * 16;
    f32x2 win[16], y[16];
#pragma unroll
    for (int j = 0; j < 16; j++) {
        ushort2 h = su[(tl0 + j) * 64 + fl];
        win[j] = f32x2{bf2f(h.x), bf2f(h.y)};
        y[j] = f32x2{0.f, 0.f};
    }
#pragma unroll
    for (int tau = 0; tau < Lc; tau++) {
        float tsv = stsv[tau];
        float kr = tsv * (cr * Pr - ci * Pi);
        float ki = tsv * (cr * Pi + ci * Pr);
#pragma unroll
        for (int j = 0; j < 16; j++) {
            y[j].x += win[j].x * kr - win[j].y * ki;
            y[j].y += win[j].x * ki + win[j].y * kr;
        }
#pragma unroll
        for (int j = 15; j >= 1; j--) win[j] = win[j - 1];
        ushort2 h = su[(tl0 - tau - 1) * 64 + fl];   // >= row 0 always
        win[0] = f32x2{bf2f(h.x), bf2f(h.y)};
        float bsv = sbsv[tau];
        float er = ar * bsv, ei = ai * bsv;
        float nPr = Pr * er - Pi * ei;
        float nPi = Pr * ei + Pi * er;
        Pr = nPr; Pi = nPi;
    }
#pragma unroll
    for (int j = 0; j < 16; j++) {
        size_t row = (size_t)(b * Tt + t0 + ty * 16 + j);
        spec[row * (2 * NFf) + f0 + fl]       = f2bf(y[j].x);
        spec[row * (2 * NFf) + NFf + f0 + fl] = f2bf(y[j].y);
    }
}

// ---------------------------------------------------------------- launch
extern "C" void kernel_launch(void* const* d_in, const int* in_sizes, int n_in,
                              void* d_out, int out_size, void* d_ws, size_t ws_size,
                              hipStream_t stream)
{
    const float* x        = (const float*)d_in[0];
    const float* norm_g   = (const float*)d_in[1];
    const float* norm_b   = (const float*)d_in[2];
    const float* Wconcept = (const float*)d_in[3];
    const float* bconcept = (const float*)d_in[4];
    const float* Wcg      = (const float*)d_in[5];
    const float* bcg      = (const float*)d_in[6];
    const float* Wfg      = (const float*)d_in[7];
    const float* bfg      = (const float*)d_in[8];
    const float* Wtg      = (const float*)d_in[9];
    const float* btg      = (const float*)d_in[10];
    const float* Wband    = (const float*)d_in[11];
    const float* bband    = (const float*)d_in[12];
    const float* Wsp      = (const float*)d_in[13];
    const float* fi       = (const float*)d_in[14];
    const float* logd     = (const float*)d_in[15];
    const float* freqs    = (const float*)d_in[16];
    const float* dtv      = (const float*)d_in[17];
    const float* Wgate    = (const float*)d_in[18];
    const float* bgate    = (const float*)d_in[19];
    const float* Wfs      = (const float*)d_in[20];
    const float* osc      = (const float*)d_in[21];
    const float* n2g      = (const float*)d_in[22];
    const float* n2b      = (const float*)d_in[23];
    const float* W1       = (const float*)d_in[24];
    const float* b1       = (const float*)d_in[25];
    const float* W2       = (const float*)d_in[26];
    const float* b2       = (const float*)d_in[27];

    char* ws = (char*)d_ws;
    size_t off = 0;
    auto alloc = [&](size_t bytes) { size_t c = off; off += (bytes + 255) & ~(size_t)255; return c; };
    size_t o_wcat = alloc((size_t)NZz * Dd * 2);
    size_t o_bias = alloc((size_t)NZz * 4);
    size_t o_wfs  = alloc((size_t)Dd * 2 * NFf * 2);
    size_t o_w1   = alloc((size_t)4 * Dd * Dd * 2);
    size_t o_w2   = alloc((size_t)4 * Dd * Dd * 2);
    size_t o_xn   = alloc((size_t)Mm * Dd * 2);
    size_t o_Z    = alloc((size_t)Mm * NZz * 2);        // reused for h
    size_t o_u    = alloc((size_t)Mm * NFf * 4);        // x2b (bf16)
    size_t o_spec = alloc((size_t)Mm * Dd * 2);         // spectral; later xn2
    size_t o_ps   = alloc((size_t)8 * Mm * 8);          // LN2 partial sums (f32x2)
    size_t o_rr   = alloc(NFf * 4);
    size_t o_ri   = alloc(NFf * 4);
    size_t o_Ar   = alloc(NFf * 4);
    size_t o_Ai   = alloc(NFf * 4);
    if (ws_size < off) return;

    u16*    wcat = (u16*)(ws + o_wcat);
    float*  bias = (float*)(ws + o_bias);
    u16*    wfs  = (u16*)(ws + o_wfs);
    u16*    w1b  = (u16*)(ws + o_w1);
    u16*    w2b  = (u16*)(ws + o_w2);
    u16*    xn   = (u16*)(ws + o_xn);
    u16*    Zb   = (u16*)(ws + o_Z);
    u16*    hb   = (u16*)(ws + o_Z);
    u16*    x2b  = (u16*)(ws + o_u);
    u16*    spec = (u16*)(ws + o_spec);
    u16*    xn2  = (u16*)(ws + o_spec);
    f32x2*  psums = (f32x2*)(ws + o_ps);
    float*  rr   = (float*)(ws + o_rr);
    float*  ri   = (float*)(ws + o_ri);
    float*  Ar   = (float*)(ws + o_Ar);
    float*  Ai   = (float*)(ws + o_Ai);

    // 1) freq consts + wcat conversion + LN1
    prep_all<<<1 + NWB_CAT + Mm, 256, 0, stream>>>(
        Wconcept, Wcg, Wfg, Wgate, Wsp, Wtg, Wband,
        bconcept, bcg, bfg, bgate, btg, bband,
        fi, logd, freqs, dtv,
        x, norm_g, norm_b,
        wcat, bias, rr, ri, Ar, Ai, xn);

    // 2) fused projection GEMM (Z = xn @ wcat^T + bias) + wfs/w1/w2 conversion
    gemm_cvt0<<<NG2 + NCVT, 256, 0, stream>>>(
        xn, wcat, bias, (void*)Zb, Mm, NZz, Dd,
        Wfs, W1, W2, wfs, w1b, w2b);

    // 3) truncated causal convolution (u from Z on the fly, in-kernel k recurrence)
    conv_kernel<<<dim3(NFf / 64, Tt / 64, Bb), 256, 0, stream>>>(
        Zb, Ar, Ai, rr, ri, spec);

    // 4) P2-GEMM with fused fuse2 epilogue (x2b + LN2 partial sums); P2 never hits HBM
    gemm5_fuse<<<dim3(Mm / 128, Dd / 128), 256, 0, stream>>>(
        spec, wfs, (void*)x2b, Mm, Dd, 2 * NFf,
        x, Zb, osc, psums);

    // 5) LN2 finish: xn2 = LN(x2b) using partial sums
    ln2_finish<<<Mm, 256, 0, stream>>>(psums, x2b, n2g, n2b, xn2);

    // 6) MLP
    gemm_bt<2><<<dim3(Mm / 128, (4 * Dd) / 128), 256, 0, stream>>>(
        xn2, w1b, b1, nullptr, (void*)hb, Mm, 4 * Dd, Dd);
    gemm_bt<3><<<dim3(Mm / 128, Dd / 128), 256, 0, stream>>>(
        hb, w2b, b2, x2b, d_out, Mm, Dd, 4 * Dd);
}

// Round 9
// 496.928 us; speedup vs baseline: 1.0193x; 1.0019x over previous
//
#include <hip/hip_runtime.h>
#include <hip/hip_bf16.h>
#include <cstdint>
#include <cstddef>

typedef unsigned short u16;
typedef unsigned int u32;
typedef short bf16x8 __attribute__((ext_vector_type(8)));
typedef float f32x4 __attribute__((ext_vector_type(4)));
typedef float f32x2 __attribute__((ext_vector_type(2)));

static constexpr int Bb = 4, Tt = 2048, Dd = 1024, NFf = 512, NBb = 4;
static constexpr int Mm = Bb * Tt;      // 8192 tokens
static constexpr int NZz = 4736;        // packed projection width (4613 padded to 37*128)
static constexpr int Lc = 32;           // conv kernel support (|A|<=0.59 -> 0.59^32 ~ 5e-8)

#define DEV __device__ __forceinline__

typedef const __attribute__((address_space(1))) u32* gas_p;
typedef __attribute__((address_space(3))) u32* las_p;

DEV u16 f2bf(float f) {
    uint32_t u = __float_as_uint(f);
    u = (u + 0x7FFF + ((u >> 16) & 1)) >> 16;   // RNE
    return (u16)u;
}
DEV float bf2f(u16 h) { return __uint_as_float(((uint32_t)h) << 16); }
DEV float sigm(float x) { return 1.0f / (1.0f + __expf(-x)); }
DEV float gelu_ex(float t) { return 0.5f * t * (1.0f + erff(t * 0.70710678118f)); }

// ---------------------------------------------------------------- sizes
static constexpr int NW0 = NZz * Dd;        // wcat elements
static constexpr int NW1 = Dd * 2 * NFf;    // wfs
static constexpr int NW2 = 4 * Dd * Dd;     // w1
static constexpr int NW3 = 4 * Dd * Dd;     // w2
static constexpr int NWB_CAT = NW0 / 1024;  // wcat convert blocks (float4 per thread)
static constexpr int NCVT = (NW1 + NW2 + NW3) / 1024;   // 9216 deferred convert blocks
static constexpr int NB_GW = 256;           // gW1/bb1 GEMV blocks (16 outputs each)

// ---------------------------------------------------------------- prep_all: freq consts + wcat cvt + LN1 + gW1/bb1 GEMV
__global__ __launch_bounds__(256) void prep_all(
    const float* __restrict__ Wconcept, const float* __restrict__ Wcg,
    const float* __restrict__ Wfg, const float* __restrict__ Wgate,
    const float* __restrict__ Wsp, const float* __restrict__ Wtg,
    const float* __restrict__ Wband,
    const float* __restrict__ bconcept, const float* __restrict__ bcg,
    const float* __restrict__ bfg, const float* __restrict__ bgate,
    const float* __restrict__ btg, const float* __restrict__ bband,
    const float* __restrict__ fi, const float* __restrict__ logd,
    const float* __restrict__ freqs, const float* __restrict__ dtv,
    const float* __restrict__ x, const float* __restrict__ norm_g,
    const float* __restrict__ norm_b,
    const float* __restrict__ n2g, const float* __restrict__ n2b,
    const float* __restrict__ b1v, const float* __restrict__ W1,
    u16* __restrict__ wcat, float* __restrict__ bias_cat,
    float* __restrict__ rr, float* __restrict__ ri,
    float* __restrict__ Ar, float* __restrict__ Ai,
    u16* __restrict__ xn,
    float* __restrict__ gW1, float* __restrict__ bb1)
{
    const int bx = blockIdx.x;
    if (bx == 0) {
        __shared__ float red[256];
        int t = threadIdx.x;
        float v0 = fi[t], v1 = fi[t + 256];
        red[t] = fmaxf(v0, v1); __syncthreads();
        for (int s = 128; s; s >>= 1) { if (t < s) red[t] = fmaxf(red[t], red[t + s]); __syncthreads(); }
        float mx = red[0]; __syncthreads();
        float e0 = expf(v0 - mx), e1 = expf(v1 - mx);
        red[t] = e0 + e1; __syncthreads();
        for (int s = 128; s; s >>= 1) { if (t < s) red[t] += red[t + s]; __syncthreads(); }
        float inv = 1.0f / red[0];
#pragma unroll
        for (int k = 0; k < 2; k++) {
            int f = t + k * 256;
            float e = k ? e1 : e0;
            float decay = sigm(logd[f]) * (e * inv * (float)NFf);
            float omega = freqs[f] * 0.1f * (sigm(dtv[f]) * 2.0f);
            float cc = cosf(omega), ss = sinf(omega);
            rr[f] = cc; ri[f] = ss; Ar[f] = decay * cc; Ai[f] = decay * ss;
        }
        return;
    }
    if (bx <= NWB_CAT) {
        const int i = ((bx - 1) * 256 + threadIdx.x) * 4;   // 4 consecutive elements of wcat
        int r = i >> 10, c = i & 1023;
        float4 v = {0.f, 0.f, 0.f, 0.f};
        if      (r < 1024) v = *(const float4*)(Wconcept + r * 1024 + c);
        else if (r < 2048) v = *(const float4*)(Wcg + (r - 1024) * 1024 + c);
        else if (r < 2560) v = *(const float4*)(Wfg + (r - 2048) * 1024 + c);
        else if (r < 3584) v = *(const float4*)(Wgate + (r - 2560) * 1024 + c);
        else if (r < 4608) v = *(const float4*)(Wsp + (r - 3584) * 1024 + c);
        else if (r == 4608) v = *(const float4*)(Wtg + c);
        else if (r < 4613) v = *(const float4*)(Wband + (r - 4609) * 1024 + c);
        *(ushort4*)(wcat + i) = ushort4{f2bf(v.x), f2bf(v.y), f2bf(v.z), f2bf(v.w)};
        if (c == 0) {
            float bv;
            if      (r < 1024) bv = bconcept[r];
            else if (r < 2048) bv = bcg[r - 1024];
            else if (r < 2560) bv = bfg[r - 2048];
            else if (r < 3584) bv = bgate[r - 2560];
            else if (r < 4608) bv = 0.0f;
            else if (r == 4608) bv = btg[0];
            else if (r < 4613) bv = bband[r - 4609];
            else bv = 0.0f;
            bias_cat[r] = bv;
        }
        return;
    }
    if (bx > NWB_CAT + Mm) {
        // gW1[n] = g2 . W1[n,:], bb1[n] = b2 . W1[n,:] + b1[n] — 16 outputs per block
        const int nb = bx - (NWB_CAT + Mm + 1);   // 0..NB_GW-1
        const int t = threadIdx.x;
        float4 g4 = *(const float4*)(n2g + t * 4);
        float4 b4 = *(const float4*)(n2b + t * 4);
        __shared__ float rg[8], rb[8];
        for (int k = 0; k < 16; k++) {
            const int n = nb * 16 + k;
            float4 wv = *(const float4*)(W1 + (size_t)n * 1024 + t * 4);
            float sg = wv.x * g4.x + wv.y * g4.y + wv.z * g4.z + wv.w * g4.w;
            float sb = wv.x * b4.x + wv.y * b4.y + wv.z * b4.z + wv.w * b4.w;
            for (int o = 32; o; o >>= 1) { sg += __shfl_down(sg, o); sb += __shfl_down(sb, o); }
            int lane = t & 63, wi = t >> 6;
            if (!lane) { rg[wi] = sg; rb[wi] = sb; }
            __syncthreads();
            if (t == 0) {
                gW1[n] = rg[0] + rg[1] + rg[2] + rg[3];
                bb1[n] = rb[0] + rb[1] + rb[2] + rb[3] + b1v[n];
            }
            __syncthreads();
        }
        return;
    }
    // LN1 role: one block per token row
    const int m = bx - NWB_CAT - 1, tid = threadIdx.x;
    float4 v = ((const float4*)(x + (size_t)m * Dd))[tid];
    float s1 = v.x + v.y + v.z + v.w;
    float s2 = v.x * v.x + v.y * v.y + v.z * v.z + v.w * v.w;
    __shared__ float lds[16];
    for (int o = 32; o; o >>= 1) { s1 += __shfl_down(s1, o); s2 += __shfl_down(s2, o); }
    int lane = tid & 63, w = tid >> 6;
    if (!lane) { lds[w] = s1; lds[8 + w] = s2; }
    __syncthreads();
    s1 = lds[0] + lds[1] + lds[2] + lds[3];
    s2 = lds[8] + lds[9] + lds[10] + lds[11];
    float mean = s1 * (1.0f / Dd);
    float var  = s2 * (1.0f / Dd) - mean * mean;
    float rstd = rsqrtf(var + 1e-5f);
    float4 gv = ((const float4*)norm_g)[tid];
    float4 bv = ((const float4*)norm_b)[tid];
    ushort4 o;
    o.x = f2bf((v.x - mean) * rstd * gv.x + bv.x);
    o.y = f2bf((v.y - mean) * rstd * gv.y + bv.y);
    o.z = f2bf((v.z - mean) * rstd * gv.z + bv.z);
    o.w = f2bf((v.w - mean) * rstd * gv.w + bv.w);
    ((ushort4*)(xn + (size_t)m * Dd))[tid] = o;
}

// ---------------------------------------------------------------- GEMM body (bf16 MFMA, BK=64, xor-swizzled LDS)
// MODE 0: bf16 = acc + bias[n]   MODE 4: bf16 = acc
// MODE 3: f32 = acc + bias[n] + bf2f(addb[m,n])
// MODE 5: fuse2 epilogue via LDS transpose (smA MUST be contiguous 32 KB [128][128], smB = smA + 128*64)
// MODE 6: LN2-folded MLP-up: A = x2b, Bw = W1∘g (bf16); prologue derives per-row mean/rstd
//         from psums; epilogue: bf16 = gelu(rstd*acc + bias[n] - mean*rstd*gW1v[n])
template<int MODE>
DEV void gemm_body(int m0, int n0,
                   u16* __restrict__ smA, u16* __restrict__ smB,
                   const u16* __restrict__ A, const u16* __restrict__ Bw,
                   const float* __restrict__ bias, const u16* __restrict__ addb,
                   void* __restrict__ Cout, int M, int N, int K,
                   const float* __restrict__ xres = nullptr,
                   const u16* __restrict__ Zf = nullptr,
                   const float* __restrict__ oscp = nullptr,
                   f32x2* __restrict__ psums = nullptr,
                   const float* __restrict__ gW1v = nullptr)
{
    __shared__ f32x2 sLN[128];                     // MODE 6 row stats (mean, rstd)
    const int tid = threadIdx.x;
    const int w = tid >> 6, lane = tid & 63;
    const int wr = w >> 1, wc = w & 1;
    const int quad = lane >> 4, l16 = lane & 15;

    if constexpr (MODE == 6) {
        if (tid < 128) {
            const int gm = m0 + tid;
            float a = 0.f, b = 0.f;
#pragma unroll
            for (int c = 0; c < 8; c++) { f32x2 p = psums[(size_t)c * Mm + gm]; a += p.x; b += p.y; }
            float mean = a * (1.0f / Dd);
            float var  = b * (1.0f / Dd) - mean * mean;
            sLN[tid] = f32x2{mean, rsqrtf(var + 1e-5f)};
        }
        __syncthreads();
    }

    // staging: thread t -> tile row (t>>3) + 32*j; global chunk (t&7)^(row&7) (swizzle)
    const int r0 = tid >> 3;                       // 0..31
    const int cs = (tid & 7) ^ (r0 & 7);
    const u16* gA = A + (size_t)(m0 + r0) * K + cs * 8;
    const u16* gB = Bw + (size_t)(n0 + r0) * K + cs * 8;

    const int swzf = l16 & 7;                      // fragment-read swizzle (row&7)

    f32x4 acc[4][4];
#pragma unroll
    for (int i = 0; i < 4; i++)
#pragma unroll
        for (int j = 0; j < 4; j++) acc[i][j] = {0.f, 0.f, 0.f, 0.f};

    for (int k0 = 0; k0 < K; k0 += 64) {
        __syncthreads();
#pragma unroll
        for (int j = 0; j < 4; j++) {
            __builtin_amdgcn_global_load_lds((gas_p)(gA + k0 + (size_t)(j * 32) * K),
                                             (las_p)(smA + j * 2048 + tid * 8), 16, 0, 0);
            __builtin_amdgcn_global_load_lds((gas_p)(gB + k0 + (size_t)(j * 32) * K),
                                             (las_p)(smB + j * 2048 + tid * 8), 16, 0, 0);
        }
        __syncthreads();
#pragma unroll
        for (int seg = 0; seg < 2; seg++) {
            bf16x8 af[4], bfv[4];
#pragma unroll
            for (int mi = 0; mi < 4; mi++)
                af[mi] = *(const bf16x8*)&smA[(wr * 64 + mi * 16 + l16) * 64 +
                                              (((seg * 4 + quad) ^ swzf) * 8)];
#pragma unroll
            for (int ni = 0; ni < 4; ni++)
                bfv[ni] = *(const bf16x8*)&smB[(wc * 64 + ni * 16 + l16) * 64 +
                                               (((seg * 4 + quad) ^ swzf) * 8)];
#pragma unroll
            for (int mi = 0; mi < 4; mi++)
#pragma unroll
                for (int ni = 0; ni < 4; ni++)
                    acc[mi][ni] = __builtin_amdgcn_mfma_f32_16x16x32_bf16(
                        af[mi], bfv[ni], acc[mi][ni], 0, 0, 0);
        }
    }

    if constexpr (MODE == 5) {
        // phase 1: dump C-tile (bf16) into the contiguous 32 KB LDS at smA
        u16* smC = smA;
        __syncthreads();
#pragma unroll
        for (int mi = 0; mi < 4; mi++)
#pragma unroll
            for (int ni = 0; ni < 4; ni++) {
                const int lr = wr * 64 + mi * 16 + quad * 4;
                const int lc = wc * 64 + ni * 16 + l16;
#pragma unroll
                for (int r = 0; r < 4; r++)
                    smC[(lr + r) * 128 + lc] = f2bf(acc[mi][ni][r]);
            }
        __syncthreads();
        // phase 2: row-major vectorized epilogue; thread t -> rows (t>>4)+16k, cols (t&15)*8..+7
        const float os = oscp[0];
        const int tr = tid >> 4, tc = tid & 15;
        u16* ob = (u16*)Cout;
#pragma unroll
        for (int rb = 0; rb < 8; rb++) {
            const int row = rb * 16 + tr;
            const int gm = m0 + row;
            const int gn0 = n0 + tc * 8;
            const u16* zr = Zf + (size_t)gm * NZz;
            const float* xr = xres + (size_t)gm * Dd;
            float4 xv0 = *(const float4*)(xr + gn0);
            float4 xv1 = *(const float4*)(xr + gn0 + 4);
            ushort4 c0 = *(const ushort4*)(zr + gn0);
            ushort4 c1 = *(const ushort4*)(zr + gn0 + 4);
            ushort4 g0 = *(const ushort4*)(zr + 1024 + gn0);
            ushort4 g1 = *(const ushort4*)(zr + 1024 + gn0 + 4);
            ushort4 a0 = *(const ushort4*)(zr + 2560 + gn0);
            ushort4 a1 = *(const ushort4*)(zr + 2560 + gn0 + 4);
            const u16* pp = &smC[row * 128 + tc * 8];
            float s1 = 0.f, s2 = 0.f;
            ushort4 o0, o1;
#pragma unroll
            for (int j = 0; j < 4; j++) {
                float p = bf2f(pp[j]);
                float v = (&xv0.x)[j] + 0.5f * (p * os * sigm(bf2f((&a0.x)[j])) +
                                                bf2f((&c0.x)[j]) * sigm(bf2f((&g0.x)[j])));
                s1 += v; s2 += v * v;
                (&o0.x)[j] = f2bf(v);
            }
#pragma unroll
            for (int j = 0; j < 4; j++) {
                float p = bf2f(pp[4 + j]);
                float v = (&xv1.x)[j] + 0.5f * (p * os * sigm(bf2f((&a1.x)[j])) +
                                                bf2f((&c1.x)[j]) * sigm(bf2f((&g1.x)[j])));
                s1 += v; s2 += v * v;
                (&o1.x)[j] = f2bf(v);
            }
            *(ushort4*)(ob + (size_t)gm * Dd + gn0)     = o0;
            *(ushort4*)(ob + (size_t)gm * Dd + gn0 + 4) = o1;
            // reduce across the 16 tc-lanes (same row)
#pragma unroll
            for (int o = 1; o < 16; o <<= 1) {
                s1 += __shfl_xor(s1, o); s2 += __shfl_xor(s2, o);
            }
            if (tc == 0) psums[(size_t)(n0 >> 7) * Mm + gm] = f32x2{s1, s2};
        }
        return;
    }

    if constexpr (MODE == 6) {
#pragma unroll
        for (int mi = 0; mi < 4; mi++) {
#pragma unroll
            for (int ni = 0; ni < 4; ni++) {
                const int gn = n0 + wc * 64 + ni * 16 + l16;
                const int lr0 = wr * 64 + mi * 16 + quad * 4;
                const int gm0 = m0 + lr0;
                const float bb = bias[gn];       // bb1 = b@W1^T + b1
                const float gw = gW1v[gn];       // g@W1^T
                float t[4];
#pragma unroll
                for (int r = 0; r < 4; r++) {
                    f32x2 st = sLN[lr0 + r];     // (mean, rstd)
                    t[r] = gelu_ex(st.y * acc[mi][ni][r] + bb - st.x * st.y * gw);
                }
                __hip_bfloat162 h01 = __float22bfloat162_rn(float2{t[0], t[1]});
                __hip_bfloat162 h23 = __float22bfloat162_rn(float2{t[2], t[3]});
                __hip_bfloat16* o = (__hip_bfloat16*)Cout;
                o[(size_t)(gm0 + 0) * N + gn] = h01.x;
                o[(size_t)(gm0 + 1) * N + gn] = h01.y;
                o[(size_t)(gm0 + 2) * N + gn] = h23.x;
                o[(size_t)(gm0 + 3) * N + gn] = h23.y;
            }
        }
        return;
    }

#pragma unroll
    for (int mi = 0; mi < 4; mi++) {
#pragma unroll
        for (int ni = 0; ni < 4; ni++) {
            const int gn = n0 + wc * 64 + ni * 16 + l16;
            const int gm0 = m0 + wr * 64 + mi * 16 + quad * 4;
            if constexpr (MODE == 0 || MODE == 4) {
                float bv = (MODE == 4) ? 0.0f : bias[gn];
                float t0 = acc[mi][ni][0] + bv, t1 = acc[mi][ni][1] + bv;
                float t2 = acc[mi][ni][2] + bv, t3 = acc[mi][ni][3] + bv;
                __hip_bfloat162 h01 = __float22bfloat162_rn(float2{t0, t1});
                __hip_bfloat162 h23 = __float22bfloat162_rn(float2{t2, t3});
                __hip_bfloat16* o = (__hip_bfloat16*)Cout;
                o[(size_t)(gm0 + 0) * N + gn] = h01.x;
                o[(size_t)(gm0 + 1) * N + gn] = h01.y;
                o[(size_t)(gm0 + 2) * N + gn] = h23.x;
                o[(size_t)(gm0 + 3) * N + gn] = h23.y;
            } else {
#pragma unroll
                for (int r = 0; r < 4; r++) {
                    const int gm = gm0 + r;
                    ((float*)Cout)[(size_t)gm * N + gn] =
                        acc[mi][ni][r] + bias[gn] + bf2f(addb[(size_t)gm * N + gn]);
                }
            }
        }
    }
}

template<int MODE>
__global__ __launch_bounds__(256, 3) void gemm_bt(
    const u16* __restrict__ A, const u16* __restrict__ Bw,
    const float* __restrict__ bias, const u16* __restrict__ addb,
    void* __restrict__ Cout, int M, int N, int K,
    f32x2* __restrict__ psums, const float* __restrict__ gW1v)
{
    __shared__ __align__(16) u16 smA[128 * 64];   // 16 KB
    __shared__ __align__(16) u16 smB[128 * 64];   // 16 KB
    gemm_body<MODE>(blockIdx.x * 128, blockIdx.y * 128, smA, smB,
                    A, Bw, bias, addb, Cout, M, N, K,
                    nullptr, nullptr, nullptr, psums, gW1v);
}

// fat step-2 kernel: gemm blocks first (1D linearized, x-major like the 2D grid),
// then deferred wfs/w1/w2 conversion blocks fill CU slots as gemm blocks retire.
// w1 conversion folds the LN2 gain: w1g[n][d] = bf16(W1[n][d] * n2g[d]).
static constexpr int NG2 = (Mm / 128) * (NZz / 128);   // 2368 gemm blocks, gx=64
__global__ __launch_bounds__(256, 3) void gemm_cvt0(
    const u16* __restrict__ A, const u16* __restrict__ Bw,
    const float* __restrict__ bias, void* __restrict__ Cout,
    int M, int N, int K,
    const float* __restrict__ Wfs, const float* __restrict__ W1,
    const float* __restrict__ W2, const float* __restrict__ n2g,
    u16* __restrict__ wfs, u16* __restrict__ w1b, u16* __restrict__ w2b)
{
    const int bid = blockIdx.x;
    if (bid < NG2) {
        __shared__ __align__(16) u16 smA[128 * 64];
        __shared__ __align__(16) u16 smB[128 * 64];
        gemm_body<0>((bid & 63) * 128, (bid >> 6) * 128, smA, smB,
                     A, Bw, bias, nullptr, Cout, M, N, K);
        return;
    }
    const int i = (bid - NG2) * 1024 + threadIdx.x * 4;
    if (i < NW1) {
        float4 v = *(const float4*)(Wfs + i);
        *(ushort4*)(wfs + i) = ushort4{f2bf(v.x), f2bf(v.y), f2bf(v.z), f2bf(v.w)};
    } else if (i < NW1 + NW2) {
        int j = i - NW1;
        float4 v = *(const float4*)(W1 + j);
        float4 g = *(const float4*)(n2g + (j & 1023));
        *(ushort4*)(w1b + j) = ushort4{f2bf(v.x * g.x), f2bf(v.y * g.y),
                                       f2bf(v.z * g.z), f2bf(v.w * g.w)};
    } else {
        int j = i - NW1 - NW2;
        float4 v = *(const float4*)(W2 + j);
        *(ushort4*)(w2b + j) = ushort4{f2bf(v.x), f2bf(v.y), f2bf(v.z), f2bf(v.w)};
    }
}

// gemm5 with fused fuse2 epilogue (MODE 5). Contiguous 32 KB LDS for the C-transpose.
__global__ __launch_bounds__(256, 3) void gemm5_fuse(
    const u16* __restrict__ A, const u16* __restrict__ Bw,
    void* __restrict__ Cout, int M, int N, int K,
    const float* __restrict__ xres, const u16* __restrict__ Zf,
    const float* __restrict__ oscp, f32x2* __restrict__ psums)
{
    __shared__ __align__(16) u16 smX[128 * 128];   // 32 KB contiguous
    gemm_body<5>(blockIdx.x * 128, blockIdx.y * 128, smX, smX + 128 * 64,
                 A, Bw, nullptr, nullptr, Cout, M, N, K,
                 xres, Zf, oscp, psums);
}

// ---------------------------------------------------------------- conv: u from Z on the fly; in-kernel k recurrence
__global__ __launch_bounds__(256) void conv_kernel(
    const u16* __restrict__ Z,
    const float* __restrict__ Ar, const float* __restrict__ Ai,
    const float* __restrict__ rr, const float* __restrict__ ri,
    u16* __restrict__ spec)
{
    __shared__ ushort2 su[96 * 64];   // 24.5 KB: u rows t0-32 .. t0+63 (bf16 pair)
    __shared__ float stsv[Lc], sbsv[Lc];
    const int tid = threadIdx.x;
    const int fl = tid & 63;
    const int ty = tid >> 6;          // 0..3
    const int f0 = blockIdx.x * 64;
    const int t0 = blockIdx.y * 64;
    const int b  = blockIdx.z;
    const int band = f0 >> 7;         // uniform within a 64-freq block

    // stage lane-uniform temporal/band strengths for the 32 taps
    if (tid < Lc) {
        stsv[tid] = sigm(bf2f(Z[(size_t)(b * Tt + tid) * NZz + 4608]));
    } else if (tid < 2 * Lc) {
        int tau = tid - Lc;
        sbsv[tau] = sigm(bf2f(Z[(size_t)(b * Tt + tau) * NZz + 4609 + band]));
    }
    // stage u = sp * sigmoid(fg) rows (bf16); 2 freqs per thread, vectorized
    for (int i = tid; i < 96 * 32; i += 256) {
        int r = i >> 5, fp = (i & 31) * 2;
        int t = t0 - 32 + r;
        ushort4 v{0, 0, 0, 0};
        if (t >= 0) {
            const u16* zr = Z + (size_t)(b * Tt + t) * NZz;
            ushort2 fg2 = *(const ushort2*)(zr + 2048 + f0 + fp);
            ushort2 sr2 = *(const ushort2*)(zr + 3584 + f0 + fp);
            ushort2 si2 = *(const ushort2*)(zr + 4096 + f0 + fp);
            float g0 = sigm(bf2f(fg2.x)), g1 = sigm(bf2f(fg2.y));
            v.x = f2bf(bf2f(sr2.x) * g0); v.y = f2bf(bf2f(si2.x) * g0);
            v.z = f2bf(bf2f(sr2.y) * g1); v.w = f2bf(bf2f(si2.y) * g1);
        }
        *(ushort4*)&su[r * 64 + fp] = v;
    }
    __syncthreads();

    // per-lane recurrence state for freq f0+fl
    const float ar = Ar[f0 + fl], ai = Ai[f0 + fl];
    const float cr = rr[f0 + fl], ci = ri[f0 + fl];
    float Pr = 1.0f, Pi = 0.0f;

    const int tl0 = 32 + ty * 16;
    f32x2 win[16], y[16];
#pragma unroll
    for (int j = 0; j < 16; j++) {
        ushort2 h = su[(tl0 + j) * 64 + fl];
        win[j] = f32x2{bf2f(h.x), bf2f(h.y)};
        y[j] = f32x2{0.f, 0.f};
    }
#pragma unroll
    for (int tau = 0; tau < Lc; tau++) {
        float tsv = stsv[tau];
        float kr = tsv * (cr * Pr - ci * Pi);
        float ki = tsv * (cr * Pi + ci * Pr);
#pragma unroll
        for (int j = 0; j < 16; j++) {
            y[j].x += win[j].x * kr - win[j].y * ki;
            y[j].y += win[j].x * ki + win[j].y * kr;
        }
#pragma unroll
        for (int j = 15; j >= 1; j--) win[j] = win[j - 1];
        ushort2 h = su[(tl0 - tau - 1) * 64 + fl];   // >= row 0 always
        win[0] = f32x2{bf2f(h.x), bf2f(h.y)};
        float bsv = sbsv[tau];
        float er = ar * bsv, ei = ai * bsv;
        float nPr = Pr * er - Pi * ei;
        float nPi = Pr * ei + Pi * er;
        Pr = nPr; Pi = nPi;
    }
#pragma unroll
    for (int j = 0; j < 16; j++) {
        size_t row = (size_t)(b * Tt + t0 + ty * 16 + j);
        spec[row * (2 * NFf) + f0 + fl]       = f2bf(y[j].x);
        spec[row * (2 * NFf) + NFf + f0 + fl] = f2bf(y[j].y);
    }
}

// ---------------------------------------------------------------- launch
extern "C" void kernel_launch(void* const* d_in, const int* in_sizes, int n_in,
                              void* d_out, int out_size, void* d_ws, size_t ws_size,
                              hipStream_t stream)
{
    const float* x        = (const float*)d_in[0];
    const float* norm_g   = (const float*)d_in[1];
    const float* norm_b   = (const float*)d_in[2];
    const float* Wconcept = (const float*)d_in[3];
    const float* bconcept = (const float*)d_in[4];
    const float* Wcg      = (const float*)d_in[5];
    const float* bcg      = (const float*)d_in[6];
    const float* Wfg      = (const float*)d_in[7];
    const float* bfg      = (const float*)d_in[8];
    const float* Wtg      = (const float*)d_in[9];
    const float* btg      = (const float*)d_in[10];
    const float* Wband    = (const float*)d_in[11];
    const float* bband    = (const float*)d_in[12];
    const float* Wsp      = (const float*)d_in[13];
    const float* fi       = (const float*)d_in[14];
    const float* logd     = (const float*)d_in[15];
    const float* freqs    = (const float*)d_in[16];
    const float* dtv      = (const float*)d_in[17];
    const float* Wgate    = (const float*)d_in[18];
    const float* bgate    = (const float*)d_in[19];
    const float* Wfs      = (const float*)d_in[20];
    const float* osc      = (const float*)d_in[21];
    const float* n2g      = (const float*)d_in[22];
    const float* n2b      = (const float*)d_in[23];
    const float* W1       = (const float*)d_in[24];
    const float* b1       = (const float*)d_in[25];
    const float* W2       = (const float*)d_in[26];
    const float* b2       = (const float*)d_in[27];

    char* ws = (char*)d_ws;
    size_t off = 0;
    auto alloc = [&](size_t bytes) { size_t c = off; off += (bytes + 255) & ~(size_t)255; return c; };
    size_t o_wcat = alloc((size_t)NZz * Dd * 2);
    size_t o_bias = alloc((size_t)NZz * 4);
    size_t o_wfs  = alloc((size_t)Dd * 2 * NFf * 2);
    size_t o_w1   = alloc((size_t)4 * Dd * Dd * 2);
    size_t o_w2   = alloc((size_t)4 * Dd * Dd * 2);
    size_t o_xn   = alloc((size_t)Mm * Dd * 2);
    size_t o_Z    = alloc((size_t)Mm * NZz * 2);        // reused for h
    size_t o_u    = alloc((size_t)Mm * NFf * 4);        // x2b (bf16)
    size_t o_spec = alloc((size_t)Mm * Dd * 2);         // spectral
    size_t o_ps   = alloc((size_t)8 * Mm * 8);          // LN2 partial sums (f32x2)
    size_t o_gw1  = alloc((size_t)4 * Dd * 4);          // gW1 (4096 f32)
    size_t o_bb1  = alloc((size_t)4 * Dd * 4);          // bb1 (4096 f32)
    size_t o_rr   = alloc(NFf * 4);
    size_t o_ri   = alloc(NFf * 4);
    size_t o_Ar   = alloc(NFf * 4);
    size_t o_Ai   = alloc(NFf * 4);
    if (ws_size < off) return;

    u16*    wcat = (u16*)(ws + o_wcat);
    float*  bias = (float*)(ws + o_bias);
    u16*    wfs  = (u16*)(ws + o_wfs);
    u16*    w1b  = (u16*)(ws + o_w1);
    u16*    w2b  = (u16*)(ws + o_w2);
    u16*    xn   = (u16*)(ws + o_xn);
    u16*    Zb   = (u16*)(ws + o_Z);
    u16*    hb   = (u16*)(ws + o_Z);
    u16*    x2b  = (u16*)(ws + o_u);
    u16*    spec = (u16*)(ws + o_spec);
    f32x2*  psums = (f32x2*)(ws + o_ps);
    float*  gW1  = (float*)(ws + o_gw1);
    float*  bb1  = (float*)(ws + o_bb1);
    float*  rr   = (float*)(ws + o_rr);
    float*  ri   = (float*)(ws + o_ri);
    float*  Ar   = (float*)(ws + o_Ar);
    float*  Ai   = (float*)(ws + o_Ai);

    // 1) freq consts + wcat conversion + LN1 + gW1/bb1 GEMV
    prep_all<<<1 + NWB_CAT + Mm + NB_GW, 256, 0, stream>>>(
        Wconcept, Wcg, Wfg, Wgate, Wsp, Wtg, Wband,
        bconcept, bcg, bfg, bgate, btg, bband,
        fi, logd, freqs, dtv,
        x, norm_g, norm_b,
        n2g, n2b, b1, W1,
        wcat, bias, rr, ri, Ar, Ai, xn, gW1, bb1);

    // 2) fused projection GEMM (Z = xn @ wcat^T + bias) + wfs/w1g/w2 conversion
    gemm_cvt0<<<NG2 + NCVT, 256, 0, stream>>>(
        xn, wcat, bias, (void*)Zb, Mm, NZz, Dd,
        Wfs, W1, W2, n2g, wfs, w1b, w2b);

    // 3) truncated causal convolution (u from Z on the fly, in-kernel k recurrence)
    conv_kernel<<<dim3(NFf / 64, Tt / 64, Bb), 256, 0, stream>>>(
        Zb, Ar, Ai, rr, ri, spec);

    // 4) P2-GEMM with fused fuse2 epilogue (x2b + LN2 partial sums); P2 never hits HBM
    gemm5_fuse<<<dim3(Mm / 128, Dd / 128), 256, 0, stream>>>(
        spec, wfs, (void*)x2b, Mm, Dd, 2 * NFf,
        x, Zb, osc, psums);

    // 5) MLP-up with LN2 folded in (MODE 6): h = gelu(rstd*(x2b@w1g^T) + bb1 - mean*rstd*gW1)
    gemm_bt<6><<<dim3(Mm / 128, (4 * Dd) / 128), 256, 0, stream>>>(
        x2b, w1b, bb1, nullptr, (void*)hb, Mm, 4 * Dd, Dd, psums, gW1);

    // 6) MLP-down + residual: out = h@w2^T + b2 + x2b
    gemm_bt<3><<<dim3(Mm / 128, Dd / 128), 256, 0, stream>>>(
        hb, w2b, b2, x2b, d_out, Mm, Dd, 4 * Dd, nullptr, nullptr);
}